// Round 12
// baseline (28.034 us; speedup 1.0000x reference)
//
#include <hip/hip_runtime.h>
#include <hip/hip_bf16.h>
#include <math.h>

#define CC 8
#define BB 4096
#define DD 512
#define SLOT_STRIDE (BB * DD)   // elements between (c,v) slots
#define NBLK (BB / 8)           // 512 blocks, 8 columns each (2 per wave)
#define LSTRIDE 65              // f32x4 per slot per half (64 + 1 pad)

constexpr float INV_T    = 10.0f;    // 1 / 0.1
constexpr float NORM_EPS = 1e-12f;

typedef __attribute__((ext_vector_type(8))) short bf16x8;  // 8 bf16 (4 VGPRs)
typedef __attribute__((ext_vector_type(4))) float f32x4;   // 4 fp32 acc / loads

__device__ __forceinline__ short f2bf(float x) {           // RNE, proven in R4
    union { __hip_bfloat16 h; short s; } u;
    u.h = __float2bfloat16(x);
    return u.s;
}

// One wave per batch column (2 columns sequentially per wave; 512 blocks =
// single occupancy pass at 2 blocks/CU). R12 experiment: DRAM page locality.
// Previous rounds loaded fragments directly (each instruction = 16 slots x
// 64B, 8MB apart -> scattered 64B page visits, ~5.4 TB/s). Now each load
// instruction reads 1KB FULLY CONTIGUOUS from one slot (16x better page
// locality), bounced through a per-wave LDS region; fragments are read back
// slot-major (slot = lane&15, per the MFMA A/B mapping). Half-column staging
// (16 slots x 1KB) keeps LDS at 66.5KB/block; half-B global loads remain in
// flight under half-A's LDS write/read/MFMA phase.
// Gram G = X X^T via 16x16x32 bf16 MFMA with A-frag == B-frag; any shared
// element->k permutation cancels exactly. Norms exact in f32.
// No fences/atomics (R7/R8: per-block agent-scope coherence ~ +60-110us).
__global__ __launch_bounds__(256, 2)
void ntxent_mfma(const float* __restrict__ inp, float* __restrict__ partial) {
    const int lane = threadIdx.x & 63;
    const int wv   = threadIdx.x >> 6;      // wave in block: 0..3
    const int slot = lane & 15;             // vector index = MFMA row & col
    const int kg   = lane >> 4;             // quarter-wave 0..3

    // per-wave private LDS staging region (no __syncthreads needed)
    __shared__ f32x4 lds[4 * 16 * LSTRIDE];          // 66560 B
    f32x4* wlds = &lds[wv * 16 * LSTRIDE];

    const int rd_lo = slot * LSTRIDE + kg;           // + 8t
    const int rd_hi = slot * LSTRIDE + 4 + kg;       // + 8t

    float lsum = 0.f;

#pragma unroll 1                            // one column's regs live at a time
    for (int cc2 = 0; cc2 < 2; ++cc2) {
        const int b = blockIdx.x * 8 + 4 * cc2 + wv;   // batch column

        // ---- phase 1: 32 fully-contiguous 1KB loads, back-to-back ----
        // instr (h,s): lane ll reads f32x4 #(64h + ll) of slot s's row
        f32x4 A[16], B[16];
#pragma unroll
        for (int s = 0; s < 16; ++s) {
            const f32x4* p4 = reinterpret_cast<const f32x4*>(
                inp + (size_t)s * SLOT_STRIDE + (size_t)b * DD);
            A[s] = p4[lane];              // half 0: elements [0,256)
        }
#pragma unroll
        for (int s = 0; s < 16; ++s) {
            const f32x4* p4 = reinterpret_cast<const f32x4*>(
                inp + (size_t)s * SLOT_STRIDE + (size_t)b * DD);
            B[s] = p4[64 + lane];         // half 1: elements [256,512)
        }

        f32x4 acc0 = {0.f, 0.f, 0.f, 0.f};
        f32x4 acc1 = {0.f, 0.f, 0.f, 0.f};
        float n2a = 0.f, n2b = 0.f;

        // ---- half A: stage to LDS, read fragments, norms+cvt+MFMA ----
#pragma unroll
        for (int s = 0; s < 16; ++s)
            wlds[s * LSTRIDE + lane] = A[s];     // waits vmcnt for A only
#pragma unroll
        for (int t = 0; t < 8; ++t) {
            const f32x4 lo = wlds[rd_lo + 8 * t];
            const f32x4 hi = wlds[rd_hi + 8 * t];
            n2a = fmaf(lo.x, lo.x, n2a);
            n2a = fmaf(lo.y, lo.y, n2a);
            n2a = fmaf(lo.z, lo.z, n2a);
            n2a = fmaf(lo.w, lo.w, n2a);
            n2b = fmaf(hi.x, hi.x, n2b);
            n2b = fmaf(hi.y, hi.y, n2b);
            n2b = fmaf(hi.z, hi.z, n2b);
            n2b = fmaf(hi.w, hi.w, n2b);
            bf16x8 f;
            f[0] = f2bf(lo.x); f[1] = f2bf(lo.y); f[2] = f2bf(lo.z); f[3] = f2bf(lo.w);
            f[4] = f2bf(hi.x); f[5] = f2bf(hi.y); f[6] = f2bf(hi.z); f[7] = f2bf(hi.w);
            if (t & 1)
                acc1 = __builtin_amdgcn_mfma_f32_16x16x32_bf16(f, f, acc1, 0, 0, 0);
            else
                acc0 = __builtin_amdgcn_mfma_f32_16x16x32_bf16(f, f, acc0, 0, 0, 0);
        }

        // ---- half B: same region (wave-private, in-order DS) ----
#pragma unroll
        for (int s = 0; s < 16; ++s)
            wlds[s * LSTRIDE + lane] = B[s];
#pragma unroll
        for (int t = 0; t < 8; ++t) {
            const f32x4 lo = wlds[rd_lo + 8 * t];
            const f32x4 hi = wlds[rd_hi + 8 * t];
            n2a = fmaf(lo.x, lo.x, n2a);
            n2a = fmaf(lo.y, lo.y, n2a);
            n2a = fmaf(lo.z, lo.z, n2a);
            n2a = fmaf(lo.w, lo.w, n2a);
            n2b = fmaf(hi.x, hi.x, n2b);
            n2b = fmaf(hi.y, hi.y, n2b);
            n2b = fmaf(hi.z, hi.z, n2b);
            n2b = fmaf(hi.w, hi.w, n2b);
            bf16x8 f;
            f[0] = f2bf(lo.x); f[1] = f2bf(lo.y); f[2] = f2bf(lo.z); f[3] = f2bf(lo.w);
            f[4] = f2bf(hi.x); f[5] = f2bf(hi.y); f[6] = f2bf(hi.z); f[7] = f2bf(hi.w);
            if (t & 1)
                acc1 = __builtin_amdgcn_mfma_f32_16x16x32_bf16(f, f, acc1, 0, 0, 0);
            else
                acc0 = __builtin_amdgcn_mfma_f32_16x16x32_bf16(f, f, acc0, 0, 0, 0);
        }
        const f32x4 acc = acc0 + acc1;

        // exact f32 norms: lanes {slot, +16, +32, +48} cover slot fully
        float n2 = n2a + n2b;
        n2 += __shfl_xor(n2, 16);
        n2 += __shfl_xor(n2, 32);
        const float invc = 1.0f / fmaxf(sqrtf(n2), NORM_EPS);  // 1/||x_slot||

        // C/D layout (m89): lane holds G[4kg + r][slot] in acc[r].
        const float inv0 = __shfl(invc, 4 * kg);       // 1/||x_{4kg}||
        const float inv2 = __shfl(invc, 4 * kg + 2);   // 1/||x_{4kg+2}||

        const float s0 = acc[0] * inv0 * invc * INV_T;  // sim[2kg  ][slot]
        const float s2 = acc[2] * inv2 * invc * INV_T;  // sim[2kg+1][slot]

        // positives: sim[2a][2a+1] on the lane whose slot == anchor_slot+1
        const int gbase = kg << 4;
        const float pos0 = __shfl(s0, gbase + 4 * kg + 1);
        const float pos1 = __shfl(s2, gbase + 4 * kg + 3);

        float e0 = ((slot >> 1) == 2 * kg)     ? 0.f : __expf(s0 - pos0);
        float e1 = ((slot >> 1) == 2 * kg + 1) ? 0.f : __expf(s2 - pos1);
#pragma unroll
        for (int m = 1; m < 16; m <<= 1) {
            e0 += __shfl_xor(e0, m);
            e1 += __shfl_xor(e1, m);
        }
        float l = __logf(1.0f + e0) + __logf(1.0f + e1);
        l += __shfl_xor(l, 16);
        l += __shfl_xor(l, 32);   // sum over all 8 anchors for column b
        lsum += l;
    }

    __shared__ float s_wsum[4];
    if (lane == 0) s_wsum[wv] = lsum;
    __syncthreads();
    if (threadIdx.x == 0)
        partial[blockIdx.x] = s_wsum[0] + s_wsum[1] + s_wsum[2] + s_wsum[3];
}

// Sum the 512 per-block partials -> scalar loss. One wave, no LDS/sync.
__global__ __launch_bounds__(64)
void ntxent_reduce(const float* __restrict__ partial, float* __restrict__ out) {
    const int lane = threadIdx.x;
    const f32x4* pv = reinterpret_cast<const f32x4*>(partial);  // 128 vec4
    const f32x4 v0 = pv[lane];
    const f32x4 v1 = pv[lane + 64];
    float s = v0.x + v0.y + v0.z + v0.w + v1.x + v1.y + v1.z + v1.w;
#pragma unroll
    for (int m = 1; m < 64; m <<= 1) s += __shfl_xor(s, m);
    if (lane == 0) out[0] = s * (1.0f / (float)(CC * BB));
}

extern "C" void kernel_launch(void* const* d_in, const int* in_sizes, int n_in,
                              void* d_out, int out_size, void* d_ws, size_t ws_size,
                              hipStream_t stream) {
    const float* inp = (const float*)d_in[0];
    float* out      = (float*)d_out;
    float* partial  = (float*)d_ws;   // NBLK floats, fully rewritten every call
    ntxent_mfma<<<dim3(NBLK), dim3(256), 0, stream>>>(inp, partial);
    ntxent_reduce<<<dim3(1), dim3(64), 0, stream>>>(partial, out);
}

// Round 13
// 27.483 us; speedup vs baseline: 1.0200x; 1.0200x over previous
//
#include <hip/hip_runtime.h>
#include <hip/hip_bf16.h>
#include <math.h>

#define CC 8
#define BB 4096
#define DD 512
#define SLOT_STRIDE (BB * DD)   // elements between (c,v) slots
#define NBLK (BB / 8)           // 512 blocks x 2 waves x 4 columns = 4096

// LDS geometry (bytes): per wave 2 buffers x 16 slots x (1KB + 16B pad)
#define SLOT_LDS 1040
#define BUF_LDS  (16 * SLOT_LDS)   // 16640
#define WAVE_LDS (2 * BUF_LDS)     // 33280

constexpr float INV_T    = 10.0f;    // 1 / 0.1
constexpr float NORM_EPS = 1e-12f;

typedef __attribute__((ext_vector_type(8))) short bf16x8;  // 8 bf16 (4 VGPRs)
typedef __attribute__((ext_vector_type(4))) float f32x4;   // 4 fp32 acc / loads

__device__ __forceinline__ short f2bf(float x) {           // RNE, proven in R4
    union { __hip_bfloat16 h; short s; } u;
    u.h = __float2bfloat16(x);
    return u.s;
}

// R13: async streaming pipeline. R11 (reg-direct) and R12 (LDS bounce) both
// sit at ~5.4 TB/s; both serialize burst(n+1) behind consume(n) (register/
// buffer WAR) -> the request queue drains at every column boundary. Here
// each half-column (16 slots x 1KB) streams via global_load_lds (16B/lane,
// wave-uniform LDS dest, per-lane global src) into a 2-buffer rotation with
// counted s_waitcnt vmcnt(16) (never 0 mid-loop, T4): burst hc+1 stays in
// flight while consume(hc) runs; issue(hc+2) follows immediately. No VGPR
// round-trip. LDS fragment read pattern identical to R12 (stride-65 f32x4
// -> 2-way bank aliasing only, free per m136).
// Gram G = X X^T via 16x16x32 bf16 MFMA with A-frag == B-frag (lane mapping
// row/col = lane&15); shared element->k permutation cancels exactly.
// Norms exact in f32. Two-kernel reduction (R7/R8: fences cost ~100us).
__global__ __launch_bounds__(128, 2)
void ntxent_mfma(const float* __restrict__ inp, float* __restrict__ partial) {
    const int lane = threadIdx.x & 63;
    const int wv   = threadIdx.x >> 6;      // wave in block: 0..1
    const int slot = lane & 15;             // vector index = MFMA row & col
    const int kg   = lane >> 4;             // quarter-wave 0..3

    __shared__ char lds_raw[2 * WAVE_LDS];  // 66560 B -> 2 blocks/CU
    char* wbase = lds_raw + wv * WAVE_LDS;  // wave-private: no __syncthreads

    // issue half-burst hc: 16 x global_load_lds, 1KB contiguous per slot
    auto issue = [&](int hc) {
        const int c = hc >> 1, h = hc & 1, p = hc & 1;
        const int b = blockIdx.x * 8 + wv * 4 + c;      // batch column
        const float* colbase = inp + (size_t)b * DD + h * 256;
        char* bufb = wbase + p * BUF_LDS;
#pragma unroll
        for (int s = 0; s < 16; ++s) {
            const float* g = colbase + (size_t)s * SLOT_STRIDE + lane * 4;
            __builtin_amdgcn_global_load_lds(
                (const __attribute__((address_space(1))) void*)g,
                (__attribute__((address_space(3))) void*)(bufb + s * SLOT_LDS),
                16, 0, 0);
        }
    };

    issue(0);
    issue(1);

    float lsum = 0.f;
    f32x4 acc0 = {0.f, 0.f, 0.f, 0.f};
    f32x4 acc1 = {0.f, 0.f, 0.f, 0.f};
    float n2a = 0.f, n2b = 0.f;

#pragma unroll
    for (int hc = 0; hc < 8; ++hc) {
        // burst hc complete; burst hc+1 (16 loads) may remain in flight
        if (hc == 7) asm volatile("s_waitcnt vmcnt(0)" ::: "memory");
        else         asm volatile("s_waitcnt vmcnt(16)" ::: "memory");
        __builtin_amdgcn_sched_barrier(0);   // rule #18: pin reads after wait

        // ---- consume buf[hc&1]: fragments, norms, cvt, MFMA ----
        const f32x4* buf4 =
            reinterpret_cast<const f32x4*>(wbase + (hc & 1) * BUF_LDS);
        const int r0 = slot * 65 + kg;       // f32x4 units; stride-65 pad
#pragma unroll
        for (int t = 0; t < 8; ++t) {
            const f32x4 lo = buf4[r0 + 8 * t];
            const f32x4 hi = buf4[r0 + 4 + 8 * t];
            n2a = fmaf(lo.x, lo.x, n2a);
            n2a = fmaf(lo.y, lo.y, n2a);
            n2a = fmaf(lo.z, lo.z, n2a);
            n2a = fmaf(lo.w, lo.w, n2a);
            n2b = fmaf(hi.x, hi.x, n2b);
            n2b = fmaf(hi.y, hi.y, n2b);
            n2b = fmaf(hi.z, hi.z, n2b);
            n2b = fmaf(hi.w, hi.w, n2b);
            bf16x8 f;
            f[0] = f2bf(lo.x); f[1] = f2bf(lo.y); f[2] = f2bf(lo.z); f[3] = f2bf(lo.w);
            f[4] = f2bf(hi.x); f[5] = f2bf(hi.y); f[6] = f2bf(hi.z); f[7] = f2bf(hi.w);
            if (t & 1)
                acc1 = __builtin_amdgcn_mfma_f32_16x16x32_bf16(f, f, acc1, 0, 0, 0);
            else
                acc0 = __builtin_amdgcn_mfma_f32_16x16x32_bf16(f, f, acc0, 0, 0, 0);
        }

        if (hc & 1) {
            // ---- column complete: epilogue (identical math to R11/R12) ----
            const f32x4 acc = acc0 + acc1;
            float n2 = n2a + n2b;
            n2 += __shfl_xor(n2, 16);
            n2 += __shfl_xor(n2, 32);
            const float invc = 1.0f / fmaxf(sqrtf(n2), NORM_EPS);

            // C/D layout (m89): lane holds G[4kg + r][slot] in acc[r]
            const float inv0 = __shfl(invc, 4 * kg);
            const float inv2 = __shfl(invc, 4 * kg + 2);
            const float s0 = acc[0] * inv0 * invc * INV_T;
            const float s2 = acc[2] * inv2 * invc * INV_T;

            const int gbase = kg << 4;
            const float pos0 = __shfl(s0, gbase + 4 * kg + 1);
            const float pos1 = __shfl(s2, gbase + 4 * kg + 3);

            float e0 = ((slot >> 1) == 2 * kg)     ? 0.f : __expf(s0 - pos0);
            float e1 = ((slot >> 1) == 2 * kg + 1) ? 0.f : __expf(s2 - pos1);
#pragma unroll
            for (int m = 1; m < 16; m <<= 1) {
                e0 += __shfl_xor(e0, m);
                e1 += __shfl_xor(e1, m);
            }
            float l = __logf(1.0f + e0) + __logf(1.0f + e1);
            l += __shfl_xor(l, 16);
            l += __shfl_xor(l, 32);
            lsum += l;
            // reset per-column accumulators
            acc0 = f32x4{0.f, 0.f, 0.f, 0.f};
            acc1 = f32x4{0.f, 0.f, 0.f, 0.f};
            n2a = 0.f; n2b = 0.f;
        }

        // refill the buffer just consumed (same parity as hc)
        if (hc < 6) {
            __builtin_amdgcn_sched_barrier(0);   // keep issue AFTER consume
            issue(hc + 2);
        }
    }

    __shared__ float s_wsum[2];
    if (lane == 0) s_wsum[wv] = lsum;
    __syncthreads();
    if (threadIdx.x == 0)
        partial[blockIdx.x] = s_wsum[0] + s_wsum[1];
}

// Sum the 512 per-block partials -> scalar loss. One wave, no LDS/sync.
__global__ __launch_bounds__(64)
void ntxent_reduce(const float* __restrict__ partial, float* __restrict__ out) {
    const int lane = threadIdx.x;
    const f32x4* pv = reinterpret_cast<const f32x4*>(partial);  // 128 vec4
    const f32x4 v0 = pv[lane];
    const f32x4 v1 = pv[lane + 64];
    float s = v0.x + v0.y + v0.z + v0.w + v1.x + v1.y + v1.z + v1.w;
#pragma unroll
    for (int m = 1; m < 64; m <<= 1) s += __shfl_xor(s, m);
    if (lane == 0) out[0] = s * (1.0f / (float)(CC * BB));
}

extern "C" void kernel_launch(void* const* d_in, const int* in_sizes, int n_in,
                              void* d_out, int out_size, void* d_ws, size_t ws_size,
                              hipStream_t stream) {
    const float* inp = (const float*)d_in[0];
    float* out      = (float*)d_out;
    float* partial  = (float*)d_ws;   // NBLK floats, fully rewritten every call
    ntxent_mfma<<<dim3(NBLK), dim3(128), 0, stream>>>(inp, partial);
    ntxent_reduce<<<dim3(1), dim3(64), 0, stream>>>(partial, out);
}